// Round 12
// baseline (29194.913 us; speedup 1.0000x reference)
//
#include <hip/hip_runtime.h>

// WaveNet autoregressive generator, MI355X. Inputs fp32, OUTPUT fp32.
// Round 12: true register residency + 1 block/CU. R11's 160-float arrays
// spilled (VGPR_Count=128) -> critical-path scratch reads; and 2-blocks/CU
// co-residency caused 23/54ms bimodality. Now: 1024-thread blocks, one layer
// each, 96 weight floats/thread (Wc0/Wc1 k-quarters, Wres/Wskip k-eighths),
// __launch_bounds__(1024,4) pins VGPR<=128 (spill-free) and 16 waves + 86KB
// LDS enforce exactly 1 block/CU. Dilation ring in LDS. 4 syncs/layer-step.
// Mailboxes: R10/R11's proven inline-asm XCD-L2 atomics, unchanged.

typedef unsigned long long u64;

#define TSTEPS 800
#define CREP 200

#define CTR_OFF 0
#define ABT_OFF 64
#define RESBOX_OFF 4096
#define BOXB 16384  // per-batch: 16 channels * 128 * 8B
#define SKIPBOX_OFF (RESBOX_OFF + 4 * BOXB)
#define WS_END (SKIPBOX_OFF + 4 * BOXB)

#define SPIN_LIMIT 1048576

// ---- XCD-L2 mailbox ops (inline asm: atomics execute in L2, always) ----
static __device__ __forceinline__ void pub64(u64* p, float x, unsigned tag) {
  const u64 v = (u64)__float_as_uint(x) | ((u64)tag << 32);
  asm volatile("global_atomic_swap_x2 %0, %1, off" ::"v"(p), "v"(v) : "memory");
}
static __device__ __forceinline__ u64 poll64(u64* p) {
  u64 old;
  const u64 z = 0;
  asm volatile("global_atomic_add_x2 %0, %1, %2, off sc0\n\ts_waitcnt vmcnt(0)"
               : "=&v"(old) : "v"(p), "v"(z) : "memory");
  return old;
}
static __device__ __forceinline__ void poll4(u64* p, u64& a, u64& b, u64& c, u64& d) {
  const u64 z = 0;
  asm volatile(
      "global_atomic_add_x2 %0, %4, %5, off sc0\n\t"
      "global_atomic_add_x2 %1, %4, %5, off offset:1024 sc0\n\t"
      "global_atomic_add_x2 %2, %4, %5, off offset:2048 sc0\n\t"
      "global_atomic_add_x2 %3, %4, %5, off offset:3072 sc0\n\t"
      "s_waitcnt vmcnt(0)"
      : "=&v"(a), "=&v"(b), "=&v"(c), "=&v"(d)
      : "v"(p), "v"(z)
      : "memory");
}
// ---- device-scope (rare, off hot path) ----
static __device__ __forceinline__ unsigned ld32(const unsigned* p) {
  return __hip_atomic_load(p, __ATOMIC_RELAXED, __HIP_MEMORY_SCOPE_AGENT);
}
static __device__ __forceinline__ void st32(unsigned* p, unsigned v) {
  __hip_atomic_store(p, v, __ATOMIC_RELAXED, __HIP_MEMORY_SCOPE_AGENT);
}
static __device__ __forceinline__ float spinf(u64* p, unsigned tag, unsigned* abt) {
  int g = 0;
  for (;;) {
    const u64 v = poll64(p);
    if ((unsigned)(v >> 32) == tag) return __uint_as_float((unsigned)v);
    if (((++g) & 255) == 0) {
      if (g > SPIN_LIMIT || ld32(abt)) { st32(abt, 1u); return 0.f; }
    }
  }
}

__global__ void wn_init(unsigned char* ws) {
  uint4 z; z.x = 0; z.y = 0; z.z = 0; z.w = 0;
  uint4* p = (uint4*)ws;
  const int n = WS_END / 16;
  for (int i = blockIdx.x * blockDim.x + threadIdx.x; i < n; i += gridDim.x * blockDim.x)
    p[i] = z;
}

__global__ __launch_bounds__(1024, 4) void wn_main(
    const float* __restrict__ enc, const float* __restrict__ Wfirst,
    const float* __restrict__ bfirst, const float* __restrict__ Wc,
    const float* __restrict__ bcv, const float* __restrict__ Wcond,
    const float* __restrict__ Wres, const float* __restrict__ bres,
    const float* __restrict__ Wskip, const float* __restrict__ bskipl,
    const float* __restrict__ Wskip0, const float* __restrict__ bskip0,
    const float* __restrict__ Wct, const float* __restrict__ Wfcw,
    const float* __restrict__ bfc, const float* __restrict__ Wlg,
    const float* __restrict__ blgg, float* __restrict__ dout,
    unsigned char* __restrict__ ws) {
  __shared__ float ringS[128 * 128];  // 64KB dilation ring (layer path)
  __shared__ float zbS[1024];         // layer: zb[4][256] / head: ct2[4][128]
  __shared__ float resS[128];
  __shared__ float zpartS[1024];      // [q][j] partials
  __shared__ float ppS[1024];         // past-term partials / head logit partials
  __shared__ float hS[128];           // h / head skS
  __shared__ float rpartS[1024];
  __shared__ float skpartS[1024];
  __shared__ float pastS[128];        // staged past input / head s1S
  __shared__ float amaxv[4];
  __shared__ int amaxi[4];
  __shared__ int argixS[1];
  __shared__ int roleS[2];

  const int tid = threadIdx.x;
  unsigned* abt = (unsigned*)(ws + ABT_OFF);

  if (tid == 0) {
    unsigned xcc;
    asm volatile("s_getreg_b32 %0, hwreg(HW_REG_XCC_ID)" : "=s"(xcc));
    int role = 999;
    if (xcc < 4)
      role = (int)__hip_atomic_fetch_add((unsigned*)(ws + CTR_OFF) + xcc, 1u,
                                         __ATOMIC_RELAXED, __HIP_MEMORY_SCOPE_AGENT);
    roleS[0] = role;
    roleS[1] = (int)xcc;
  }
  __syncthreads();
  const int role = roleS[0];
  const int b = roleS[1];
  if (role >= 17) return;

  const int jz = tid & 255, qz = tid >> 8;  // z-split: output jz, k-quarter (32)
  const int j3 = tid & 127, q8 = tid >> 7;  // r/s-split: output j3, k-eighth (16)

  if (role < 16) {
    // ================= layer block =================
    const int l = role;
    const int dl = 1 << (l & 7);

    // Register-resident weights: 32+32+16+16 = 96 floats/thread.
    float wc0q[32], wc1q[32], wresr[16], wskipr[16];
    {
      const float2* wcb = (const float2*)Wc + ((size_t)(l * 256 + jz) * 128 + qz * 32);
#pragma unroll
      for (int kk = 0; kk < 32; kk++) {
        const float2 v = wcb[kk];
        wc0q[kk] = v.x;
        wc1q[kk] = v.y;
      }
      const float4* rb = (const float4*)(Wres + (size_t)(l * 128 + j3) * 128 + q8 * 16);
      const float4* sb = (const float4*)(Wskip + (size_t)(l * 128 + j3) * 128 + q8 * 16);
#pragma unroll
      for (int m = 0; m < 4; m++) {
        const float4 v = rb[m];
        const float4 u = sb[m];
        wresr[4 * m] = v.x; wresr[4 * m + 1] = v.y;
        wresr[4 * m + 2] = v.z; wresr[4 * m + 3] = v.w;
        wskipr[4 * m] = u.x; wskipr[4 * m + 1] = u.y;
        wskipr[4 * m + 2] = u.z; wskipr[4 * m + 3] = u.w;
      }
    }
    const float bresv = bres[l * 128 + j3];

    // zb[e][j] = bc[l][j] + c_e(b) @ Wcond[l][j][:]
    if (tid < 256) {
      for (int e = 0; e < 4; e++) {
        float a = bcv[l * 256 + tid];
        for (int c = 0; c < 64; c++)
          a = fmaf(enc[(b * 64 + c) * 4 + e], Wcond[((size_t)l * 256 + tid) * 64 + c], a);
        zbS[e * 256 + tid] = a;
      }
    }
    for (int i = tid; i < 128 * 128; i += 1024) ringS[i] = 0.f;  // zero queues
    ppS[tid] = 0.f;  // past-term partials start at zero

    u64* inbox = (u64*)(ws + RESBOX_OFF + (size_t)b * BOXB) + l * 128;
    u64* outbox = (u64*)(ws + RESBOX_OFF + (size_t)b * BOXB) + ((l + 1) & 15) * 128;
    u64* skipbox = (u64*)(ws + SKIPBOX_OFF + (size_t)b * BOXB) + l * 128;
    __syncthreads();

    for (int t = 0; t < TSTEPS; t++) {
      const unsigned want = (unsigned)(t + 1);
      const int e = t / CREP;

      // A: receive res_l(t)
      if (tid < 128) resS[tid] = spinf(inbox + tid, want, abt);
      __syncthreads();

      // B: z partials (wc1q)
      {
        const float* rp = resS + qz * 32;
        float zp = 0.f;
#pragma unroll
        for (int kk = 0; kk < 32; kk++) zp = fmaf(rp[kk], wc1q[kk], zp);
        zpartS[tid] = zp;  // [qz][jz] == tid
      }
      __syncthreads();

      // C: combine -> h; ring write + stage next past input
      if (tid < 128) {
        const float g0 = zpartS[tid] + zpartS[256 + tid] + zpartS[512 + tid] +
                         zpartS[768 + tid] + ppS[tid] + ppS[256 + tid] + ppS[512 + tid] +
                         ppS[768 + tid] + zbS[e * 256 + tid];
        const int to = 128 + tid;
        const float o0 = zpartS[to] + zpartS[256 + to] + zpartS[512 + to] +
                         zpartS[768 + to] + ppS[to] + ppS[256 + to] + ppS[512 + to] +
                         ppS[768 + to] + zbS[e * 256 + to];
        hS[tid] = (1.f / (1.f + expf(-g0))) * tanhf(o0);
        ringS[(t % dl) * 128 + tid] = resS[tid];
        pastS[tid] = (dl == 1) ? resS[tid] : ringS[((t + 1) % dl) * 128 + tid];
      }
      __syncthreads();

      // D: res'/skip partials (h) + next-step past partials (pastS)
      {
        const float* hp = hS + q8 * 16;
        float rp2 = 0.f, sp = 0.f;
#pragma unroll
        for (int kk = 0; kk < 16; kk++) {
          rp2 = fmaf(hp[kk], wresr[kk], rp2);
          sp = fmaf(hp[kk], wskipr[kk], sp);
        }
        rpartS[tid] = rp2;  // [q8][j3] == tid
        skpartS[tid] = sp;
        const float* pq = pastS + qz * 32;
        float ppn = 0.f;
#pragma unroll
        for (int kk = 0; kk < 32; kk++) ppn = fmaf(pq[kk], wc0q[kk], ppn);
        ppS[tid] = ppn;
      }
      __syncthreads();

      // E: publish res' (critical path) then skip
      if (tid < 128) {
        if (l < 15) {
          float rsum = resS[tid] + bresv;
#pragma unroll
          for (int q = 0; q < 8; q++) rsum += rpartS[q * 128 + tid];
          pub64(outbox + tid, rsum, want);
        }
        float ssum = 0.f;
#pragma unroll
        for (int q = 0; q < 8; q++) ssum += skpartS[q * 128 + tid];
        pub64(skipbox + tid, ssum, want);
      }
    }
  } else {
    // ================= head block =================
    float wlgr[32], wfcr[16], wsk0r[16];
    {
      const float4* lb = (const float4*)(Wlg + (size_t)jz * 128 + qz * 32);
#pragma unroll
      for (int m = 0; m < 8; m++) {
        const float4 v = lb[m];
        wlgr[4 * m] = v.x; wlgr[4 * m + 1] = v.y;
        wlgr[4 * m + 2] = v.z; wlgr[4 * m + 3] = v.w;
      }
      const float4* fb = (const float4*)(Wfcw + (size_t)j3 * 128 + q8 * 16);
      const float4* s0b = (const float4*)(Wskip0 + (size_t)j3 * 128 + q8 * 16);
#pragma unroll
      for (int m = 0; m < 4; m++) {
        const float4 v = fb[m];
        const float4 u = s0b[m];
        wfcr[4 * m] = v.x; wfcr[4 * m + 1] = v.y;
        wfcr[4 * m + 2] = v.z; wfcr[4 * m + 3] = v.w;
        wsk0r[4 * m] = u.x; wsk0r[4 * m + 1] = u.y;
        wsk0r[4 * m + 2] = u.z; wsk0r[4 * m + 3] = u.w;
      }
    }
    float wf0 = 0.f, wf1 = 0.f, bfv = 0.f, bs0 = 0.f, bsum = 0.f, bfcv = 0.f;
    if (tid < 128) {
      wf0 = Wfirst[2 * tid]; wf1 = Wfirst[2 * tid + 1]; bfv = bfirst[tid];
      bs0 = bskip0[tid];
      for (int l2 = 0; l2 < 16; l2++) bsum += bskipl[l2 * 128 + tid];
      bfcv = bfc[tid];
      for (int e = 0; e < 4; e++) {  // ct2 -> zbS[e*128+s]
        float a = 0.f;
        for (int c = 0; c < 64; c++)
          a = fmaf(enc[(b * 64 + c) * 4 + e], Wct[tid * 64 + c], a);
        zbS[e * 128 + tid] = a;
      }
    }
    const float blgv = (tid < 256) ? blgg[tid] : 0.f;
    float fq = 0.f, x = 128.f / 127.5f - 1.f;
    u64* res0box = (u64*)(ws + RESBOX_OFF + (size_t)b * BOXB);  // layer-0 inbox
    u64* skb = (u64*)(ws + SKIPBOX_OFF + (size_t)b * BOXB);
    __syncthreads();

    for (int t = 0; t < TSTEPS; t++) {
      const unsigned want = (unsigned)(t + 1);
      const int e = t / CREP;

      // A: first causal conv; publish res0 immediately (starts the ring)
      if (tid < 128) {
        const float rv = fmaf(fq, wf0, fmaf(x, wf1, bfv));
        pub64(res0box + tid, rv, want);
        resS[tid] = rv;
      }
      __syncthreads();

      // B: skip0 partials
      {
        const float* rp = resS + q8 * 16;
        float sp = 0.f;
#pragma unroll
        for (int kk = 0; kk < 16; kk++) sp = fmaf(rp[kk], wsk0r[kk], sp);
        zpartS[tid] = sp;
      }
      __syncthreads();

      // C: combine + collect 16 per-layer skips (4x4 concurrent atomics)
      if (tid < 128) {
        float sacc = bs0 + bsum;
#pragma unroll
        for (int q = 0; q < 8; q++) sacc += zpartS[q * 128 + tid];
        u64 v[16];
        int g = 0;
        for (;;) {
          bool ok = true;
#pragma unroll
          for (int grp = 0; grp < 4; grp++)
            poll4(skb + grp * 512 + tid, v[grp * 4], v[grp * 4 + 1], v[grp * 4 + 2],
                  v[grp * 4 + 3]);
#pragma unroll
          for (int l2 = 0; l2 < 16; l2++) ok &= ((unsigned)(v[l2] >> 32) == want);
          if (ok) break;
          if (((++g) & 63) == 0) {
            if (g > (SPIN_LIMIT >> 6) || ld32(abt)) { st32(abt, 1u); break; }
          }
        }
#pragma unroll
        for (int l2 = 0; l2 < 16; l2++) sacc += __uint_as_float((unsigned)v[l2]);
        hS[tid] = fmaxf(sacc, 0.f);
      }
      __syncthreads();

      // D: s1 partials
      {
        const float* sp2 = hS + q8 * 16;
        float p = 0.f;
#pragma unroll
        for (int kk = 0; kk < 16; kk++) p = fmaf(sp2[kk], wfcr[kk], p);
        zpartS[tid] = p;
      }
      __syncthreads();

      // E: s1 combine
      if (tid < 128) {
        float p = bfcv + zbS[e * 128 + tid];
#pragma unroll
        for (int q = 0; q < 8; q++) p += zpartS[q * 128 + tid];
        pastS[tid] = fmaxf(p, 0.f);
      }
      __syncthreads();

      // F: logit partials
      {
        const float* sp3 = pastS + qz * 32;
        float p = 0.f;
#pragma unroll
        for (int kk = 0; kk < 32; kk++) p = fmaf(sp3[kk], wlgr[kk], p);
        ppS[tid] = p;  // [qz][jz]
      }
      __syncthreads();

      // G: logits + argmax (np first-max tie rule)
      float lg = 0.f;
      if (tid < 256) {
        lg = ppS[tid] + ppS[256 + tid] + ppS[512 + tid] + ppS[768 + tid] + blgv;
        float bv = lg;
        int bi = tid;
#pragma unroll
        for (int off = 32; off >= 1; off >>= 1) {
          const float ov = __shfl_down(bv, (unsigned)off);
          const int oi = __shfl_down(bi, (unsigned)off);
          if (ov > bv || (ov == bv && oi < bi)) { bv = ov; bi = oi; }
        }
        if ((tid & 63) == 0) { amaxv[tid >> 6] = bv; amaxi[tid >> 6] = bi; }
      }
      __syncthreads();
      if (tid == 0) {
        float bb = amaxv[0];
        int ii = amaxi[0];
        for (int w2 = 1; w2 < 4; w2++)
          if (amaxv[w2] > bb || (amaxv[w2] == bb && amaxi[w2] < ii)) {
            bb = amaxv[w2]; ii = amaxi[w2];
          }
        argixS[0] = ii;
      }
      __syncthreads();
      fq = x;
      x = (float)argixS[0] / 127.5f - 1.f;

      if (tid < 256) dout[((size_t)b * 256 + tid) * TSTEPS + t] = lg;
    }
  }
}

extern "C" void kernel_launch(void* const* d_in, const int* in_sizes, int n_in,
                              void* d_out, int out_size, void* d_ws, size_t ws_size,
                              hipStream_t stream) {
  (void)in_sizes; (void)n_in; (void)out_size; (void)ws_size;
  wn_init<<<64, 256, 0, stream>>>((unsigned char*)d_ws);
  wn_main<<<512, 1024, 0, stream>>>(
      (const float*)d_in[0], (const float*)d_in[1], (const float*)d_in[2],
      (const float*)d_in[3], (const float*)d_in[4], (const float*)d_in[5],
      (const float*)d_in[6], (const float*)d_in[7], (const float*)d_in[8],
      (const float*)d_in[9], (const float*)d_in[10], (const float*)d_in[11],
      (const float*)d_in[12], (const float*)d_in[13], (const float*)d_in[14],
      (const float*)d_in[15], (const float*)d_in[16],
      (float*)d_out, (unsigned char*)d_ws);
}

// Round 13
// 23623.648 us; speedup vs baseline: 1.2358x; 1.2358x over previous
//
#include <hip/hip_runtime.h>

// WaveNet autoregressive generator, MI355X. Inputs fp32, OUTPUT fp32.
// Round 13: R11 structure (best known 23.7ms) + FORCED register residency.
// R11/R12 post-mortem: __launch_bounds__ 2nd arg is only a MIN waves/EU; the
// occupancy heuristic targeted 4-8 waves/EU and spilled the weight arrays
// (R11 VGPR=128 @160 floats, R12 VGPR=64 @96 floats) -> critical-path
// matvecs read scratch. amdgpu_waves_per_eu(2,2) pins min=max=2 -> 256-VGPR
// budget, heuristic disabled. Weight arrays are float4 quads (40/thread).
// Mailboxes: R10's proven inline-asm XCD-L2 atomics, byte-identical.

typedef unsigned long long u64;

#define TSTEPS 800
#define CREP 200

#define CTR_OFF 0
#define ABT_OFF 64
#define RESBOX_OFF 4096
#define BOXB 16384  // per-batch: 16 channels * 128 * 8B
#define SKIPBOX_OFF (RESBOX_OFF + 4 * BOXB)
#define RING_OFF (SKIPBOX_OFF + 4 * BOXB)
#define RINGB 261120  // per-batch: 510 slots * 128 * 4B
#define WS_END (RING_OFF + 4 * RINGB)

#define SPIN_LIMIT 1048576

// ---- XCD-L2 mailbox ops (inline asm: atomics execute in L2, always) ----
static __device__ __forceinline__ void pub64(u64* p, float x, unsigned tag) {
  const u64 v = (u64)__float_as_uint(x) | ((u64)tag << 32);
  asm volatile("global_atomic_swap_x2 %0, %1, off" ::"v"(p), "v"(v) : "memory");
}
static __device__ __forceinline__ u64 poll64(u64* p) {
  u64 old;
  const u64 z = 0;
  asm volatile("global_atomic_add_x2 %0, %1, %2, off sc0\n\ts_waitcnt vmcnt(0)"
               : "=&v"(old) : "v"(p), "v"(z) : "memory");
  return old;
}
static __device__ __forceinline__ void poll4(u64* p, u64& a, u64& b, u64& c, u64& d) {
  const u64 z = 0;
  asm volatile(
      "global_atomic_add_x2 %0, %4, %5, off sc0\n\t"
      "global_atomic_add_x2 %1, %4, %5, off offset:1024 sc0\n\t"
      "global_atomic_add_x2 %2, %4, %5, off offset:2048 sc0\n\t"
      "global_atomic_add_x2 %3, %4, %5, off offset:3072 sc0\n\t"
      "s_waitcnt vmcnt(0)"
      : "=&v"(a), "=&v"(b), "=&v"(c), "=&v"(d)
      : "v"(p), "v"(z)
      : "memory");
}
// ---- device-scope (rare, off hot path) ----
static __device__ __forceinline__ unsigned ld32(const unsigned* p) {
  return __hip_atomic_load(p, __ATOMIC_RELAXED, __HIP_MEMORY_SCOPE_AGENT);
}
static __device__ __forceinline__ void st32(unsigned* p, unsigned v) {
  __hip_atomic_store(p, v, __ATOMIC_RELAXED, __HIP_MEMORY_SCOPE_AGENT);
}
static __device__ __forceinline__ float spinf(u64* p, unsigned tag, unsigned* abt) {
  int g = 0;
  for (;;) {
    const u64 v = poll64(p);
    if ((unsigned)(v >> 32) == tag) return __uint_as_float((unsigned)v);
    if (((++g) & 255) == 0) {
      if (g > SPIN_LIMIT || ld32(abt)) { st32(abt, 1u); return 0.f; }
    }
  }
}

__global__ void wn_init(unsigned char* ws) {
  uint4 z; z.x = 0; z.y = 0; z.z = 0; z.w = 0;
  uint4* p = (uint4*)ws;
  const int n = WS_END / 16;
  for (int i = blockIdx.x * blockDim.x + threadIdx.x; i < n; i += gridDim.x * blockDim.x)
    p[i] = z;
}

__global__ __attribute__((amdgpu_waves_per_eu(2, 2))) __launch_bounds__(512, 2) void wn_main(
    const float* __restrict__ enc, const float* __restrict__ Wfirst,
    const float* __restrict__ bfirst, const float* __restrict__ Wc,
    const float* __restrict__ bcv, const float* __restrict__ Wcond,
    const float* __restrict__ Wres, const float* __restrict__ bres,
    const float* __restrict__ Wskip, const float* __restrict__ bskipl,
    const float* __restrict__ Wskip0, const float* __restrict__ bskip0,
    const float* __restrict__ Wct, const float* __restrict__ Wfcw,
    const float* __restrict__ bfc, const float* __restrict__ Wlg,
    const float* __restrict__ blgg, float* __restrict__ dout,
    unsigned char* __restrict__ ws) {
  __shared__ __attribute__((aligned(16))) unsigned char smem[14336];
  float* zbS = (float*)smem;                   // layer: [4][256] (4KB)
  float* ct2 = (float*)smem;                   // head: [4][128] (2KB)
  float* resS = (float*)(smem + 4096);         // layer [128] / head res0S
  float* zpartS = (float*)(smem + 4608);       // [512] / head partS
  float* ppS = (float*)(smem + 6656);          // [512] / head lgS
  float* hS = (float*)(smem + 8704);           // [128] / head skS
  float* rpartS = (float*)(smem + 9216);       // [512] / head s1S[128]
  float* skpartS = (float*)(smem + 11264);     // [512]
  float* pastS = (float*)(smem + 13312);       // [128]
  float* amaxv = (float*)(smem + 13824);       // [4]
  int* amaxi = (int*)(smem + 13840);           // [4]
  int* argixS = (int*)(smem + 13856);
  int* roleS = (int*)(smem + 13872);

  const int tid = threadIdx.x;
  unsigned* abt = (unsigned*)(ws + ABT_OFF);

  if (tid == 0) {
    unsigned xcc;
    asm volatile("s_getreg_b32 %0, hwreg(HW_REG_XCC_ID)" : "=s"(xcc));
    int role = 999;
    if (xcc < 4)
      role = (int)__hip_atomic_fetch_add((unsigned*)(ws + CTR_OFF) + xcc, 1u,
                                         __ATOMIC_RELAXED, __HIP_MEMORY_SCOPE_AGENT);
    roleS[0] = role;
    roleS[1] = (int)xcc;
  }
  __syncthreads();
  const int role = roleS[0];
  const int b = roleS[1];
  if (role >= 17) return;

  const int jz = tid & 255, kh = tid >> 8;        // z-split: output jz, k-half kh
  const int j3 = tid & 127, q3 = tid >> 7;        // r-split: output j3, k-quarter q3

  if (role < 16) {
    // ================= layer block =================
    const int l = role;
    const int dl = 1 << (l & 7);
    const int pfx = (l < 8) ? ((1 << l) - 1) : (254 + (1 << (l - 8)));

    // Register-resident weights: 16+16+8 float4 = 160 floats/thread.
    float4 wc1h[16], wc0h[16];
    float4 wresq[8];
    {
      const float4* wbase = (const float4*)(Wc + ((size_t)(l * 256 + jz) * 128 + kh * 64) * 2);
#pragma unroll
      for (int m = 0; m < 16; m++) {
        const float4 v0 = wbase[2 * m];      // {tap0(k), tap1(k), tap0(k+1), tap1(k+1)}
        const float4 v1 = wbase[2 * m + 1];  // {tap0(k+2), tap1(k+2), tap0(k+3), tap1(k+3)}
        float4 w0, w1;
        w0.x = v0.x; w0.y = v0.z; w0.z = v1.x; w0.w = v1.z;
        w1.x = v0.y; w1.y = v0.w; w1.z = v1.y; w1.w = v1.w;
        wc0h[m] = w0;
        wc1h[m] = w1;
      }
      const float4* rbase = (const float4*)(Wres + (size_t)(l * 128 + j3) * 128 + q3 * 32);
#pragma unroll
      for (int m = 0; m < 8; m++) wresq[m] = rbase[m];
    }
    const float bresv = bres[l * 128 + j3];

    // zb[e][j] = bc[l][j] + c_e(b) @ Wcond[l][j][:]  (tid<256)
    if (tid < 256) {
      for (int e = 0; e < 4; e++) {
        float a = bcv[l * 256 + tid];
        for (int c = 0; c < 64; c++)
          a = fmaf(enc[(b * 64 + c) * 4 + e], Wcond[((size_t)l * 256 + tid) * 64 + c], a);
        zbS[e * 256 + tid] = a;
      }
    }
    ppS[tid] = 0.f;  // past-term partials start at zero (zero queues)

    u64* inbox = (u64*)(ws + RESBOX_OFF + (size_t)b * BOXB) + l * 128;
    u64* outbox = (u64*)(ws + RESBOX_OFF + (size_t)b * BOXB) + ((l + 1) & 15) * 128;
    u64* skipbox = (u64*)(ws + SKIPBOX_OFF + (size_t)b * BOXB) + l * 128;
    float* ringf = (float*)(ws + RING_OFF + (size_t)b * RINGB) + pfx * 128;
    const float4* wskb = (const float4*)(Wskip + (size_t)(l * 128 + j3) * 128 + q3 * 32);
    __syncthreads();

    for (int t = 0; t < TSTEPS; t++) {
      const unsigned want = (unsigned)(t + 1);
      const int e = t / CREP;

      if (tid < 128) resS[tid] = spinf(inbox + tid, want, abt);
      __syncthreads();

      // z partials: zpart[kh][jz] = sum_k res[kh*64+k] * Wc1[jz][kh*64+k]
      {
        const float4* r4 = (const float4*)(resS + kh * 64);
        float zp = 0.f;
#pragma unroll
        for (int m = 0; m < 16; m++) {
          const float4 r = r4[m];
          const float4 w = wc1h[m];
          zp = fmaf(r.x, w.x, zp);
          zp = fmaf(r.y, w.y, zp);
          zp = fmaf(r.z, w.z, zp);
          zp = fmaf(r.w, w.w, zp);
        }
        zpartS[(kh << 8) | jz] = zp;
      }
      __syncthreads();
      if (tid < 128) {
        const float g0 = zpartS[tid] + zpartS[256 + tid] + ppS[tid] + ppS[256 + tid] +
                         zbS[e * 256 + tid];
        const float o0 = zpartS[128 + tid] + zpartS[384 + tid] + ppS[128 + tid] +
                         ppS[384 + tid] + zbS[e * 256 + 128 + tid];
        hS[tid] = (1.f / (1.f + expf(-g0))) * tanhf(o0);
      }
      __syncthreads();

      // res' partials: rpart[q3][j3] = sum_k h[q3*32+k] * Wres[j3][q3*32+k]
      {
        const float4* h4 = (const float4*)(hS + q3 * 32);
        float rp2 = 0.f;
#pragma unroll
        for (int m = 0; m < 8; m++) {
          const float4 hv = h4[m];
          const float4 w = wresq[m];
          rp2 = fmaf(hv.x, w.x, rp2);
          rp2 = fmaf(hv.y, w.y, rp2);
          rp2 = fmaf(hv.z, w.z, rp2);
          rp2 = fmaf(hv.w, w.w, rp2);
        }
        rpartS[(q3 << 7) | j3] = rp2;
      }
      __syncthreads();
      if (l < 15 && tid < 128)
        pub64(outbox + tid,
              resS[tid] + rpartS[tid] + rpartS[128 + tid] + rpartS[256 + tid] +
                  rpartS[384 + tid] + bresv,
              want);

      // ---- off critical path ----
      // skip partials (Wskip streamed; L2-resident)
      {
        const float4* h4 = (const float4*)(hS + q3 * 32);
        float sp = 0.f;
#pragma unroll
        for (int m = 0; m < 8; m++) {
          const float4 wv = wskb[m];
          const float4 hv = h4[m];
          sp = fmaf(wv.x, hv.x, sp);
          sp = fmaf(wv.y, hv.y, sp);
          sp = fmaf(wv.z, hv.z, sp);
          sp = fmaf(wv.w, hv.w, sp);
        }
        skpartS[(q3 << 7) | j3] = sp;
      }
      __syncthreads();
      if (tid < 128)
        pub64(skipbox + tid,
              skpartS[tid] + skpartS[128 + tid] + skpartS[256 + tid] + skpartS[384 + tid],
              want);

      // res history ring; stage next step's past input
      if (tid < 128) {
        ringf[(t % dl) * 128 + tid] = resS[tid];
        pastS[tid] = (dl == 1) ? resS[tid] : ringf[((t + 1) % dl) * 128 + tid];
      }
      __syncthreads();
      // next step's past-term partials (VGPR wc0h)
      {
        const float4* p4 = (const float4*)(pastS + kh * 64);
        float ppn = 0.f;
#pragma unroll
        for (int m = 0; m < 16; m++) {
          const float4 pv = p4[m];
          const float4 w = wc0h[m];
          ppn = fmaf(pv.x, w.x, ppn);
          ppn = fmaf(pv.y, w.y, ppn);
          ppn = fmaf(pv.z, w.z, ppn);
          ppn = fmaf(pv.w, w.w, ppn);
        }
        ppS[(kh << 8) | jz] = ppn;
      }
    }
  } else {
    // ================= head block =================
    float4 wlgr[16], wfcr[8], wsk0[8];
    {
      const float4* lb = (const float4*)(Wlg + (size_t)jz * 128 + kh * 64);
#pragma unroll
      for (int m = 0; m < 16; m++) wlgr[m] = lb[m];
      const float4* fb = (const float4*)(Wfcw + (size_t)j3 * 128 + q3 * 32);
      const float4* sb = (const float4*)(Wskip0 + (size_t)j3 * 128 + q3 * 32);
#pragma unroll
      for (int m = 0; m < 8; m++) {
        wfcr[m] = fb[m];
        wsk0[m] = sb[m];
      }
    }
    float wf0 = 0.f, wf1 = 0.f, bfv = 0.f, bs0 = 0.f, bsum = 0.f, bfcv = 0.f;
    if (tid < 128) {
      wf0 = Wfirst[2 * tid]; wf1 = Wfirst[2 * tid + 1]; bfv = bfirst[tid];
      bs0 = bskip0[tid];
      for (int l2 = 0; l2 < 16; l2++) bsum += bskipl[l2 * 128 + tid];
      bfcv = bfc[tid];
      for (int e = 0; e < 4; e++) {
        float a = 0.f;
        for (int c = 0; c < 64; c++)
          a = fmaf(enc[(b * 64 + c) * 4 + e], Wct[tid * 64 + c], a);
        ct2[e * 128 + tid] = a;
      }
    }
    const float blgv = (tid < 256) ? blgg[tid] : 0.f;
    float fq = 0.f, x = 128.f / 127.5f - 1.f;
    u64* res0box = (u64*)(ws + RESBOX_OFF + (size_t)b * BOXB);  // layer-0 inbox
    u64* skb = (u64*)(ws + SKIPBOX_OFF + (size_t)b * BOXB);
    float* res0S = resS;
    float* partS = zpartS;  // [512]
    float* lgS = ppS;       // [512]
    float* skS = hS;        // [128]
    float* s1S = rpartS;    // [128]
    __syncthreads();

    for (int t = 0; t < TSTEPS; t++) {
      const unsigned want = (unsigned)(t + 1);
      const int e = t / CREP;

      // first causal conv; publish res0 immediately (starts the ring)
      if (tid < 128) {
        const float rv = fmaf(fq, wf0, fmaf(x, wf1, bfv));
        pub64(res0box + tid, rv, want);
        res0S[tid] = rv;
      }
      __syncthreads();

      // skip0 partials (VGPR wsk0)
      {
        const float4* r4 = (const float4*)(res0S + q3 * 32);
        float sp = 0.f;
#pragma unroll
        for (int m = 0; m < 8; m++) {
          const float4 rv = r4[m];
          const float4 w = wsk0[m];
          sp = fmaf(rv.x, w.x, sp);
          sp = fmaf(rv.y, w.y, sp);
          sp = fmaf(rv.z, w.z, sp);
          sp = fmaf(rv.w, w.w, sp);
        }
        partS[tid] = sp;  // tid == q3*128 + j3
      }
      __syncthreads();
      if (tid < 128) {
        float sacc = partS[tid] + partS[128 + tid] + partS[256 + tid] + partS[384 + tid] +
                     bs0 + bsum;
        // poll all 16 per-layer skip boxes (4 groups x 4 concurrent atomics)
        u64 v[16];
        int g = 0;
        for (;;) {
          bool ok = true;
#pragma unroll
          for (int grp = 0; grp < 4; grp++)
            poll4(skb + grp * 512 + tid, v[grp * 4], v[grp * 4 + 1], v[grp * 4 + 2],
                  v[grp * 4 + 3]);
#pragma unroll
          for (int l2 = 0; l2 < 16; l2++) ok &= ((unsigned)(v[l2] >> 32) == want);
          if (ok) break;
          if (((++g) & 63) == 0) {
            if (g > (SPIN_LIMIT >> 6) || ld32(abt)) { st32(abt, 1u); break; }
          }
        }
#pragma unroll
        for (int l2 = 0; l2 < 16; l2++) sacc += __uint_as_float((unsigned)v[l2]);
        skS[tid] = fmaxf(sacc, 0.f);
      }
      __syncthreads();

      // s1 partials: relu(skip) @ Wfc
      {
        const float4* s4 = (const float4*)(skS + q3 * 32);
        float p = 0.f;
#pragma unroll
        for (int m = 0; m < 8; m++) {
          const float4 sv = s4[m];
          const float4 w = wfcr[m];
          p = fmaf(sv.x, w.x, p);
          p = fmaf(sv.y, w.y, p);
          p = fmaf(sv.z, w.z, p);
          p = fmaf(sv.w, w.w, p);
        }
        partS[tid] = p;
      }
      __syncthreads();
      if (tid < 128)
        s1S[tid] = fmaxf(partS[tid] + partS[128 + tid] + partS[256 + tid] +
                             partS[384 + tid] + bfcv + ct2[e * 128 + tid],
                         0.f);
      __syncthreads();

      // logit partials: relu(s1) @ Wlogits
      {
        const float4* s4 = (const float4*)(s1S + kh * 64);
        float p = 0.f;
#pragma unroll
        for (int m = 0; m < 16; m++) {
          const float4 sv = s4[m];
          const float4 w = wlgr[m];
          p = fmaf(sv.x, w.x, p);
          p = fmaf(sv.y, w.y, p);
          p = fmaf(sv.z, w.z, p);
          p = fmaf(sv.w, w.w, p);
        }
        lgS[(kh << 8) | jz] = p;
      }
      __syncthreads();

      float lg = 0.f;
      if (tid < 256) lg = lgS[tid] + lgS[256 + tid] + blgv;

      // argmax over 256 classes (tid<256, np first-max tie rule)
      {
        float bv = lg;
        int bi = tid;
#pragma unroll
        for (int off = 32; off >= 1; off >>= 1) {
          const float ov = __shfl_down(bv, (unsigned)off);
          const int oi = __shfl_down(bi, (unsigned)off);
          if (ov > bv || (ov == bv && oi < bi)) { bv = ov; bi = oi; }
        }
        if (tid < 256 && (tid & 63) == 0) { amaxv[tid >> 6] = bv; amaxi[tid >> 6] = bi; }
      }
      __syncthreads();
      if (tid == 0) {
        float bb = amaxv[0];
        int ii = amaxi[0];
        for (int w2 = 1; w2 < 4; w2++)
          if (amaxv[w2] > bb || (amaxv[w2] == bb && amaxi[w2] < ii)) {
            bb = amaxv[w2]; ii = amaxi[w2];
          }
        argixS[0] = ii;
      }
      __syncthreads();
      fq = x;
      x = (float)argixS[0] / 127.5f - 1.f;

      if (tid < 256) dout[((size_t)b * 256 + tid) * TSTEPS + t] = lg;
    }
  }
}

extern "C" void kernel_launch(void* const* d_in, const int* in_sizes, int n_in,
                              void* d_out, int out_size, void* d_ws, size_t ws_size,
                              hipStream_t stream) {
  (void)in_sizes; (void)n_in; (void)out_size; (void)ws_size;
  wn_init<<<256, 256, 0, stream>>>((unsigned char*)d_ws);
  wn_main<<<1024, 512, 0, stream>>>(
      (const float*)d_in[0], (const float*)d_in[1], (const float*)d_in[2],
      (const float*)d_in[3], (const float*)d_in[4], (const float*)d_in[5],
      (const float*)d_in[6], (const float*)d_in[7], (const float*)d_in[8],
      (const float*)d_in[9], (const float*)d_in[10], (const float*)d_in[11],
      (const float*)d_in[12], (const float*)d_in[13], (const float*)d_in[14],
      (const float*)d_in[15], (const float*)d_in[16],
      (float*)d_out, (unsigned char*)d_ws);
}